// Round 8
// baseline (349.134 us; speedup 1.0000x reference)
//
#include <hip/hip_runtime.h>
#include <math.h>

// Round 8: persistent double-buffered assembly.
// R7 post-mortem: 2-blocks/CU was neutral -> the bubble is per-band phase
// serialization (zero/barrier/gather/barrier/write/drain) + p1's 1.53-round
// grid. Fix:
//  P1: 256 blocks x 1024, each EXACTLY 2 chunks of ceil(m/512) pairs (perfect
//      balance). Bin into stage[2048 4-row buckets][8] (64B line slots,
//      sentinel-padded); flush full lines; LDS overflow -> per-2-row-band
//      L2-resident lists (4096 cursors, ~23 atomics/line).
//  P2: 256 blocks x 1024, each owns 16 consecutive 2-row bands, TWO 64KiB LDS
//      buffers: write band t from cur (rezero in same pass) WHILE gathering
//      band t+1 into nxt; 1 barrier/band. Consecutive bands share the parent
//      4-row bucket slice -> the 2x gather redundancy is an L2 hit, not HBM.
// entry = uint2{ key=(row<<13)|col, f32 bits }, SENT=0xFFFFFFFF (>>14 never
// matches a band). d=2^13 -> flat out index == key.

#define NCHUNK   512
#define NBKT     2048          // 4-row buckets
#define BCAP     8             // slot = one 64B line
#define NB2      4096          // 2-row bands
#define BANDS_PB 16            // bands per p2 block
#define OVB      512
#define OVCAP    64
#define SENTK    0xFFFFFFFFu
#define GCAP     65536

// ---------------------------------------------------------------- fused path

__global__ __launch_bounds__(1024) void p1_kernel(
    const int*   __restrict__ idx,     // [2, M] int32
    const float* __restrict__ vals,    // [M]
    float scale, int m, int cs,        // cs = chunk size in pairs
    uint2* __restrict__ region1,       // [NBKT][NCHUNK][BCAP]
    uint2* __restrict__ ovfreg,        // [NB2][OVCAP]
    int*   __restrict__ ovfcur,        // [NB2]
    uint2* __restrict__ glist,         // [GCAP] never-path
    int*   __restrict__ ghdr)
{
    __shared__ uint2 stage[NBKT][BCAP];    // 128 KiB
    __shared__ int   cnt[NBKT];            // 8 KiB
    __shared__ uint2 ovfst[OVB];           // 4 KiB
    __shared__ int   ovfn;
    uint2* sflat = &stage[0][0];
    const int tid = threadIdx.x;

    for (int c = 0; c < 2; ++c) {
        const int chunk = blockIdx.x * 2 + c;

        for (int f = tid; f < NBKT * BCAP; f += 1024) sflat[f] = make_uint2(SENTK, 0u);
        for (int b = tid; b < NBKT; b += 1024) cnt[b] = 0;
        if (tid == 0) ovfn = 0;
        __syncthreads();

        const int base = chunk * cs;
        int end = base + cs; if (end > m) end = m;
        for (int k = base + tid; k < end; k += 1024) {
            int i = idx[k];
            int j = idx[m + k];
            unsigned vb = __float_as_uint(vals[k] * scale);

            unsigned k1 = ((unsigned)i << 13) | (unsigned)j;
            int b1 = i >> 2;
            int p = atomicAdd(&cnt[b1], 1);
            if (p < BCAP) stage[b1][p] = make_uint2(k1, vb);
            else { int q = atomicAdd(&ovfn, 1);
                   if (q < OVB) ovfst[q] = make_uint2(k1, vb);
                   else { int g = atomicAdd(ghdr, 1); if (g < GCAP) glist[g] = make_uint2(k1, vb); } }

            unsigned k2 = ((unsigned)j << 13) | (unsigned)i;
            int b2 = j >> 2;
            p = atomicAdd(&cnt[b2], 1);
            if (p < BCAP) stage[b2][p] = make_uint2(k2, vb);
            else { int q = atomicAdd(&ovfn, 1);
                   if (q < OVB) ovfst[q] = make_uint2(k2, vb);
                   else { int g = atomicAdd(ghdr, 1); if (g < GCAP) glist[g] = make_uint2(k2, vb); } }
        }
        __syncthreads();

        // flush: 8 consecutive threads write one full 64B line per bucket slot
        for (int f = tid; f < NBKT * BCAP; f += 1024) {
            int bkt = f >> 3, e = f & 7;
            region1[((long long)bkt * NCHUNK + chunk) * BCAP + e] = sflat[f];
        }
        int n = ovfn; if (n > OVB) n = OVB;
        for (int e = tid; e < n; e += 1024) {
            uint2 en = ovfst[e];
            int band = en.x >> 14;
            int pos = atomicAdd(&ovfcur[band], 1);
            if (pos < OVCAP) ovfreg[band * OVCAP + pos] = en;
            else { int g = atomicAdd(ghdr, 1); if (g < GCAP) glist[g] = en; }
        }
        __syncthreads();                 // stage/ovfst reused next chunk
    }
}

__device__ __forceinline__ void gather_band(
    float* __restrict__ buf,
    int band,
    const uint2* __restrict__ region1,
    const uint2* __restrict__ ovfreg,
    const int*   __restrict__ ovfcur,
    const uint2* __restrict__ glist,
    int gn,
    const float* __restrict__ h_local,
    int tid)
{
    const uint4* src = reinterpret_cast<const uint4*>(
        region1 + (long long)(band >> 1) * NCHUNK * BCAP);
    const unsigned bu = (unsigned)band;
    for (int e = tid; e < (NCHUNK * BCAP) / 2; e += 1024) {
        uint4 en = src[e];
        if ((en.x >> 14) == bu) buf[en.x & 16383] = __uint_as_float(en.y);
        if ((en.z >> 14) == bu) buf[en.z & 16383] = __uint_as_float(en.w);
    }
    int n = ovfcur[band]; if (n > OVCAP) n = OVCAP;
    for (int e = tid; e < n; e += 1024) {
        uint2 en = ovfreg[band * OVCAP + e];
        buf[en.x & 16383] = __uint_as_float(en.y);
    }
    if (gn > 0) {
        for (int e = tid; e < gn; e += 1024) {
            uint2 en = glist[e];
            if ((en.x >> 14) == bu) buf[en.x & 16383] = __uint_as_float(en.y);
        }
    }
    if (tid < 2) {
        int r = (band << 1) + tid;
        buf[((unsigned)tid << 13) | (unsigned)r] = h_local[r];
    }
}

__global__ __launch_bounds__(1024) void p2_kernel(
    float* __restrict__ out,
    const float* __restrict__ h_local,
    const uint2* __restrict__ region1,
    const uint2* __restrict__ ovfreg,
    const int*   __restrict__ ovfcur,
    const uint2* __restrict__ glist,
    const int*   __restrict__ ghdr)
{
    __shared__ float bufA[16384];              // 64 KiB
    __shared__ float bufB[16384];              // 64 KiB  -> 128 KiB total
    const int tid = threadIdx.x;
    const int b0  = blockIdx.x * BANDS_PB;

    int gn = ghdr[0]; if (gn > GCAP) gn = GCAP;

    float4* a4 = reinterpret_cast<float4*>(bufA);
    float4* b4 = reinterpret_cast<float4*>(bufB);
    const float4 z = make_float4(0.f, 0.f, 0.f, 0.f);
    for (int c = tid; c < 4096; c += 1024) { a4[c] = z; b4[c] = z; }
    __syncthreads();

    gather_band(bufA, b0, region1, ovfreg, ovfcur, glist, gn, h_local, tid);
    __syncthreads();

    for (int t = 0; t < BANDS_PB; ++t) {
        float4* cur = (t & 1) ? b4 : a4;
        float4* nxt = (t & 1) ? a4 : b4;
        const int band = b0 + t;

        // stream band t out of cur; rezero each slot in the same thread pass
        float4* orow = reinterpret_cast<float4*>(out + ((long long)band << 14));
        for (int c = tid; c < 4096; c += 1024) {
            float4 v = cur[c];
            orow[c] = v;
            cur[c] = z;
        }
        // overlap: gather band t+1 into nxt (nxt was rezeroed last iteration)
        if (t + 1 < BANDS_PB)
            gather_band(reinterpret_cast<float*>(nxt), band + 1,
                        region1, ovfreg, ovfcur, glist, gn, h_local, tid);
        __syncthreads();
    }
}

// ---------------------------------------------------------------- fallbacks

__global__ __launch_bounds__(256) void init_counts_kernel(
    float* __restrict__ out, int d, int logd)
{
    int r = blockIdx.x * blockDim.x + threadIdx.x;
    if (r < d) reinterpret_cast<int*>(out)[(long long)r << logd] = 0;
}

__global__ __launch_bounds__(256) void bin_kernel(
    float* __restrict__ out,
    const int*   __restrict__ idx,
    const float* __restrict__ vals,
    float scale, int m, int logd, int cap)
{
    int k = blockIdx.x * blockDim.x + threadIdx.x;
    if (k >= m) return;
    int i = idx[k];
    int j = idx[m + k];
    unsigned vb = __float_as_uint(vals[k] * scale);
    int* cnt_i = reinterpret_cast<int*>(out) + ((long long)i << logd);
    int* cnt_j = reinterpret_cast<int*>(out) + ((long long)j << logd);
    int p1 = atomicAdd(cnt_i, 1);
    if (p1 < cap)
        *reinterpret_cast<uint2*>(out + ((long long)i << logd) + 2 + 2 * p1) =
            make_uint2((unsigned)j, vb);
    int p2 = atomicAdd(cnt_j, 1);
    if (p2 < cap)
        *reinterpret_cast<uint2*>(out + ((long long)j << logd) + 2 + 2 * p2) =
            make_uint2((unsigned)i, vb);
}

__global__ __launch_bounds__(256) void rows_kernel(
    float* __restrict__ out,
    const float* __restrict__ h_local,
    int logd, int cap)
{
    __shared__ float srow[8192];
    const int d  = 1 << logd;
    const int n4 = d >> 2;
    float4* s4 = reinterpret_cast<float4*>(srow);
    const int r = blockIdx.x;
    float* grow = out + ((long long)r << logd);
    const float4 z = make_float4(0.f, 0.f, 0.f, 0.f);
    for (int c = threadIdx.x; c < n4; c += blockDim.x) s4[c] = z;
    __syncthreads();
    int cnt = reinterpret_cast<const int*>(grow)[0];
    if (cnt > cap) cnt = cap;
    const uint2* eb = reinterpret_cast<const uint2*>(grow + 2);
    for (int e = threadIdx.x; e < cnt; e += blockDim.x) {
        uint2 p = eb[e];
        srow[p.x] = __uint_as_float(p.y);
    }
    if (threadIdx.x == 0) srow[r] = h_local[r];
    __syncthreads();
    for (int c = threadIdx.x; c < n4; c += blockDim.x)
        reinterpret_cast<float4*>(grow)[c] = s4[c];
}

__global__ __launch_bounds__(256) void fill_diag_kernel(
    float* __restrict__ out, const float* __restrict__ h_local,
    int d, long long n)
{
    long long t = (long long)blockIdx.x * blockDim.x + threadIdx.x;
    if (t >= n) return;
    long long row = t / d;
    long long col = t - row * d;
    out[t] = (row == col) ? h_local[row] : 0.f;
}

__global__ __launch_bounds__(256) void scatter_kernel(
    float* __restrict__ out,
    const int* __restrict__ idx,
    const float* __restrict__ vals,
    float scale, int m, int d)
{
    int k = blockIdx.x * blockDim.x + threadIdx.x;
    if (k >= m) return;
    int i = idx[k];
    int j = idx[m + k];
    float v = vals[k] * scale;
    out[(long long)i * d + j] = v;
    out[(long long)j * d + i] = v;
}

// ---------------------------------------------------------------- launch

extern "C" void kernel_launch(void* const* d_in, const int* in_sizes, int n_in,
                              void* d_out, int out_size, void* d_ws, size_t ws_size,
                              hipStream_t stream) {
    const float* h_local = (const float*)d_in[0];
    const float* V_int   = (const float*)d_in[1];
    const int*   idx     = (const int*)d_in[2];

    const int d = in_sizes[0];            // 8192
    const int m = in_sizes[1];            // 1,600,000

    int logd = 0;
    while ((1 << logd) < d) ++logd;
    const bool pow2 = ((1 << logd) == d);

    const float iscale = (float)(1.0 - 0.2 / sqrt(log((double)d)));
    float* out = (float*)d_out;
    const int block = 256;

    // ws layout: [ghdr @0][ovfcur @4096: 16KB] -> memset first 20.5KB
    //            [glist 512KB @24576][ovfreg 2MB][region1 64MB]
    const size_t off_ovfcur = 4096;
    const size_t hdr_bytes  = off_ovfcur + (size_t)NB2 * 4;          // 20480
    const size_t off_glist  = 24576;
    const size_t off_ovfreg = off_glist + (size_t)GCAP * sizeof(uint2);
    const size_t off_r1     = off_ovfreg + (size_t)NB2 * OVCAP * sizeof(uint2);
    const size_t ws_need    = off_r1 + (size_t)NBKT * NCHUNK * BCAP * sizeof(uint2);

    const bool path8 = (d == 8192) && (m > 0) && (m <= 2200000) &&
                       (d_ws != nullptr) && (ws_size >= ws_need);

    if (path8) {
        char* ws = (char*)d_ws;
        int*   ghdr    = (int*)ws;
        int*   ovfcur  = (int*)(ws + off_ovfcur);
        uint2* glist   = (uint2*)(ws + off_glist);
        uint2* ovfreg  = (uint2*)(ws + off_ovfreg);
        uint2* region1 = (uint2*)(ws + off_r1);

        const int cs = (m + NCHUNK - 1) / NCHUNK;        // pairs per chunk

        hipMemsetAsync(ws, 0, hdr_bytes, stream);
        p1_kernel<<<NCHUNK / 2, 1024, 0, stream>>>(idx, V_int, iscale, m, cs,
                                                   region1, ovfreg, ovfcur,
                                                   glist, ghdr);
        p2_kernel<<<NB2 / BANDS_PB, 1024, 0, stream>>>(out, h_local, region1,
                                                       ovfreg, ovfcur, glist, ghdr);
    } else if (pow2 && d >= 1024 && d <= 8192 &&
               ((long long)m * 2 / d) < (long long)((d - 2) / 2) / 2) {
        const int cap = (d - 2) / 2;
        init_counts_kernel<<<(d + block - 1) / block, block, 0, stream>>>(out, d, logd);
        bin_kernel<<<(m + block - 1) / block, block, 0, stream>>>(out, idx, V_int,
                                                                  iscale, m, logd, cap);
        rows_kernel<<<d, block, 0, stream>>>(out, h_local, logd, cap);
    } else {
        const long long n = (long long)d * d;
        const long long grid_fill = (n + block - 1) / block;
        fill_diag_kernel<<<(dim3)(unsigned)grid_fill, block, 0, stream>>>(out, h_local, d, n);
        const int grid_sc = (m + block - 1) / block;
        scatter_kernel<<<grid_sc, block, 0, stream>>>(out, idx, V_int, iscale, m, d);
    }
}